// Round 12
// baseline (436.745 us; speedup 1.0000x reference)
//
#include <hip/hip_runtime.h>
#include <hip/hip_bf16.h>
#include <math.h>

// ---------------------------------------------------------------------------
// GATGNN global attention:  softmax_seg( MLP([x|glbl]) )  on MI355X (gfx950)
// R12 (=R11 fixed): gemm0 = BARRIER-FREE per-wave all-register pipeline
//      (64x64/wave, named double-buffer regs, imm-offset loads, no LDS).
//      Fast coalesced pack_a0 (bf16 [Mp,640]) + LDS-tiled W transposes.
//      gemm1 (proven gll16 128^2) and segsoftmax unchanged.
// ---------------------------------------------------------------------------

#define NSEG 1024

typedef __attribute__((ext_vector_type(8))) short short8;
typedef __attribute__((ext_vector_type(4))) float f32x4;

__device__ __forceinline__ unsigned short f2bf(float f) {
  __hip_bfloat16 h = __float2bfloat16(f);
  return *reinterpret_cast<unsigned short*>(&h);
}
__device__ __forceinline__ float softplus_fast(float z) {
  float t = __expf(-fabsf(z));
  return fmaxf(z, 0.f) + __logf(1.f + t);
}
__device__ __forceinline__ void gll16(const void* g, void* l) {
  __builtin_amdgcn_global_load_lds(
      (const __attribute__((address_space(1))) void*)g,
      (__attribute__((address_space(3))) void*)l, 16, 0, 0);
}
// m204 bijective XCD-chunked swizzle: each XCD owns a contiguous L-range.
__device__ __forceinline__ int xcd_swz(int bid, int nwg) {
  int q = nwg >> 3, r = nwg & 7, x = bid & 7, i = bid >> 3;
  return (x < r ? x * (q + 1) : r * (q + 1) + (x - r) * q) + i;
}

// ---------------------------------------------------------------------------
// transposeW: W [KDIM,512] f32 -> WT bf16 [512,KOUT] (k >= KDIM zero-padded).
// LDS 64x64 tile, coalesced on both sides.
// ---------------------------------------------------------------------------
template <int KDIM, int KOUT>
__global__ __launch_bounds__(256) void transposeW(const float* __restrict__ W,
                                                  unsigned short* __restrict__ WT) {
  __shared__ float lds[64][65];
  const int bk = blockIdx.x >> 3, bn = blockIdx.x & 7;   // 8 n-tiles of 64
  const int k0 = bk * 64, n0 = bn * 64;
  const int tid = threadIdx.x;
#pragma unroll
  for (int i2 = 0; i2 < 4; ++i2) {
    int f = i2 * 256 + tid;          // 1024 float4 loads
    int row = f >> 4, q = f & 15;
    int k = k0 + row;
    float4 v = float4{0.f, 0.f, 0.f, 0.f};
    if (k < KDIM) v = *reinterpret_cast<const float4*>(W + (size_t)k * 512 + n0 + q * 4);
    lds[row][q * 4 + 0] = v.x; lds[row][q * 4 + 1] = v.y;
    lds[row][q * 4 + 2] = v.z; lds[row][q * 4 + 3] = v.w;
  }
  __syncthreads();
#pragma unroll
  for (int i3 = 0; i3 < 2; ++i3) {
    int f = i3 * 256 + tid;          // 512 uint4 stores
    int row2 = f >> 3, q2 = f & 7;
    union { unsigned short u[8]; uint4 qv; } o;
#pragma unroll
    for (int j = 0; j < 8; ++j) o.u[j] = f2bf(lds[q2 * 8 + j][row2]);
    *reinterpret_cast<uint4*>(WT + (size_t)(n0 + row2) * KOUT + k0 + q2 * 8) = o.qv;
  }
}

// ---------------------------------------------------------------------------
// pack_a0: A0[Mp,640] bf16 = [bf16(x) | bf16(gx) | 0]; pad rows zero.
// Also zeros logits. Pure pow2 index math, float4/uint4 only.
// ---------------------------------------------------------------------------
__global__ __launch_bounds__(256) void pack_a0(const float* __restrict__ x,
                                               const float* __restrict__ gx,
                                               unsigned short* __restrict__ A0,
                                               float* __restrict__ logits,
                                               int N, int Mp) {
  int t = blockIdx.x * 256 + threadIdx.x;
  union { unsigned short u[8]; uint4 q; } v;
  if (t < Mp * 64) {                       // x part: cols 0..511
    int row = t >> 6, c = t & 63;
    if (row >= N) {
#pragma unroll
      for (int j = 0; j < 8; ++j) v.u[j] = 0;
    } else {
      const float4* p = (const float4*)(x + (size_t)row * 512 + c * 8);
      float4 a = p[0], b = p[1];
      v.u[0] = f2bf(a.x); v.u[1] = f2bf(a.y); v.u[2] = f2bf(a.z); v.u[3] = f2bf(a.w);
      v.u[4] = f2bf(b.x); v.u[5] = f2bf(b.y); v.u[6] = f2bf(b.z); v.u[7] = f2bf(b.w);
    }
    *reinterpret_cast<uint4*>(A0 + (size_t)row * 640 + c * 8) = v.q;
    return;
  }
  t -= Mp * 64;
  if (t < Mp * 16) {                       // gx part: cols 512..639
    int row = t >> 4, j = t & 15;          // col group 512+8j
    if (row >= N || j >= 14) {
#pragma unroll
      for (int k = 0; k < 8; ++k) v.u[k] = 0;
    } else if (j <= 12) {                  // gcols 8j..8j+7 all < 108
      const float4* p = (const float4*)(gx + (size_t)row * 108 + j * 8);
      float4 a = p[0], b = p[1];
      v.u[0] = f2bf(a.x); v.u[1] = f2bf(a.y); v.u[2] = f2bf(a.z); v.u[3] = f2bf(a.w);
      v.u[4] = f2bf(b.x); v.u[5] = f2bf(b.y); v.u[6] = f2bf(b.z); v.u[7] = f2bf(b.w);
    } else {                               // j == 13: gcols 104..107 valid
      const float4* p = (const float4*)(gx + (size_t)row * 108 + 104);
      float4 a = p[0];
      v.u[0] = f2bf(a.x); v.u[1] = f2bf(a.y); v.u[2] = f2bf(a.z); v.u[3] = f2bf(a.w);
      v.u[4] = 0; v.u[5] = 0; v.u[6] = 0; v.u[7] = 0;
    }
    *reinterpret_cast<uint4*>(A0 + (size_t)row * 640 + 512 + j * 8) = v.q;
    return;
  }
  t -= Mp * 16;
  if (t < Mp) logits[t] = 0.f;
}

// ---------------------------------------------------------------------------
// GEMM0 (barrier-free, all-register): H0 = bf16(softplus(A0 * W0T^T + b0)).
// Block = 4 independent waves; wave computes 64 rows x 64 cols (acc 4x4 f32x4).
// Per 32-K chunk: 8 global_load_dwordx4 (imm-offset) + 16 MFMA; two named
// register buffers, prefetch distance 2 chunks. NO LDS, NO barriers -> each
// wave self-paces on its own in-order vmcnt (compiler-counted waits).
// ---------------------------------------------------------------------------
#define LOAD_CHUNK(ab, wb, kb_)                                      \
  {                                                                  \
    ab[0] = *reinterpret_cast<const short8*>(aP0 + (kb_));           \
    ab[1] = *reinterpret_cast<const short8*>(aP1 + (kb_));           \
    ab[2] = *reinterpret_cast<const short8*>(aP2 + (kb_));           \
    ab[3] = *reinterpret_cast<const short8*>(aP3 + (kb_));           \
    wb[0] = *reinterpret_cast<const short8*>(wP0 + (kb_));           \
    wb[1] = *reinterpret_cast<const short8*>(wP1 + (kb_));           \
    wb[2] = *reinterpret_cast<const short8*>(wP2 + (kb_));           \
    wb[3] = *reinterpret_cast<const short8*>(wP3 + (kb_));           \
  }
#define MFMA_CHUNK(ab, wb)                                                        \
  {                                                                               \
    _Pragma("unroll") for (int mi = 0; mi < 4; ++mi)                              \
      _Pragma("unroll") for (int ni = 0; ni < 4; ++ni)                            \
        acc[mi][ni] =                                                             \
            __builtin_amdgcn_mfma_f32_16x16x32_bf16(wb[ni], ab[mi], acc[mi][ni],  \
                                                    0, 0, 0);                     \
  }

__global__ __launch_bounds__(256, 3) void gemm0_rf(const unsigned short* __restrict__ A0,
                                                   const unsigned short* __restrict__ W0T,
                                                   const float* __restrict__ b0,
                                                   unsigned short* __restrict__ H0,
                                                   int nwg) {
  constexpr int K = 640, KT = 20;
  const int L = xcd_swz(blockIdx.x, nwg);
  const int nt = L & 1, mt = L >> 1;       // 2 col-halves of 256; Mp/64 row strips
  const int tid = threadIdx.x, lane = tid & 63, wid = tid >> 6;
  const int lm = lane & 15, rch = lane >> 4;
  const int rowbase = mt * 64;
  const int colbase = nt * 256 + wid * 64;

  const unsigned short* aP0 = A0 + (size_t)(rowbase + 0 * 16 + lm) * K + rch * 8;
  const unsigned short* aP1 = A0 + (size_t)(rowbase + 1 * 16 + lm) * K + rch * 8;
  const unsigned short* aP2 = A0 + (size_t)(rowbase + 2 * 16 + lm) * K + rch * 8;
  const unsigned short* aP3 = A0 + (size_t)(rowbase + 3 * 16 + lm) * K + rch * 8;
  const unsigned short* wP0 = W0T + (size_t)(colbase + 0 * 16 + lm) * K + rch * 8;
  const unsigned short* wP1 = W0T + (size_t)(colbase + 1 * 16 + lm) * K + rch * 8;
  const unsigned short* wP2 = W0T + (size_t)(colbase + 2 * 16 + lm) * K + rch * 8;
  const unsigned short* wP3 = W0T + (size_t)(colbase + 3 * 16 + lm) * K + rch * 8;

  f32x4 acc[4][4] = {};
  short8 ab0[4], wb0[4], ab1[4], wb1[4];

  LOAD_CHUNK(ab0, wb0, 0);
  LOAD_CHUNK(ab1, wb1, 32);

#pragma unroll
  for (int kt = 0; kt < KT; kt += 2) {
    MFMA_CHUNK(ab0, wb0);
    if (kt + 2 < KT) LOAD_CHUNK(ab0, wb0, (kt + 2) * 32);
    MFMA_CHUNK(ab1, wb1);
    if (kt + 3 < KT) LOAD_CHUNK(ab1, wb1, (kt + 3) * 32);
  }

  // epilogue: thread holds C[m][n0..n0+3]
#pragma unroll
  for (int mi = 0; mi < 4; ++mi) {
    const int m = rowbase + mi * 16 + lm;
#pragma unroll
    for (int ni = 0; ni < 4; ++ni) {
      const int n0 = colbase + ni * 16 + (rch << 2);
      const f32x4 bb = *reinterpret_cast<const f32x4*>(b0 + n0);
      f32x4 v = acc[mi][ni];
      union { unsigned short u[4]; uint2 qv; } o;
#pragma unroll
      for (int rr = 0; rr < 4; ++rr) o.u[rr] = f2bf(softplus_fast(v[rr] + bb[rr]));
      *reinterpret_cast<uint2*>(H0 + (size_t)m * 512 + n0) = o.qv;
    }
  }
}

// ---------------------------------------------------------------------------
// GEMM1 (+logit fusion): logits[m] += sum_n softplus(H0*W1T^T + b1)[m][n]*W2[n]
// Proven: 128x128, BK=32, both panels bf16 via global_load_lds, 32KB LDS,
// 4 blocks/CU.
// ---------------------------------------------------------------------------
__global__ __launch_bounds__(256, 4) void gemm1(const unsigned short* __restrict__ H0,
                                                const unsigned short* __restrict__ W1T,
                                                const float* __restrict__ b1,
                                                const float* __restrict__ W2,
                                                float* __restrict__ logits, int nwg) {
  constexpr int K = 512, KT = 16;
  __shared__ unsigned short As[2][128 * 32];
  __shared__ unsigned short Ws[2][128 * 32];
  const int L = xcd_swz(blockIdx.x, nwg);
  const int nt = L & 3, mt = L >> 2;
  const int tid = threadIdx.x, lane = tid & 63, wid = tid >> 6;
  const int wm = wid >> 1, wn = wid & 1, lm = lane & 15, rch = lane >> 4;

  const unsigned short* Ag = H0 + (size_t)(mt * 128) * K;
  const unsigned short* Wg = W1T + (size_t)(nt * 128) * K;

  f32x4 acc[4][4] = {};

  auto stage = [&](int buf, int kb) {
#pragma unroll
    for (int i2 = 0; i2 < 2; ++i2) {
      int f = i2 * 256 + tid;
      int row = f >> 2;
      int sc = ((f & 3) ^ ((row >> 1) & 3)) << 3;
      gll16(Ag + (size_t)row * K + kb + sc, &As[buf][f * 8]);
      gll16(Wg + (size_t)row * K + kb + sc, &Ws[buf][f * 8]);
    }
  };

  stage(0, 0);

  for (int kt = 0; kt < KT; ++kt) {
    const int cur = kt & 1;
    __syncthreads();
    if (kt + 1 < KT) stage(cur ^ 1, (kt + 1) * 32);

    short8 af[4], wf[4];
#pragma unroll
    for (int mi = 0; mi < 4; ++mi) {
      int rw = wm * 64 + mi * 16 + lm;
      af[mi] = *reinterpret_cast<const short8*>(
          &As[cur][rw * 32 + ((rch ^ ((rw >> 1) & 3)) << 3)]);
    }
#pragma unroll
    for (int ni = 0; ni < 4; ++ni) {
      int rw = wn * 64 + ni * 16 + lm;
      wf[ni] = *reinterpret_cast<const short8*>(
          &Ws[cur][rw * 32 + ((rch ^ ((rw >> 1) & 3)) << 3)]);
    }
    __builtin_amdgcn_s_setprio(1);
#pragma unroll
    for (int mi = 0; mi < 4; ++mi)
#pragma unroll
      for (int ni = 0; ni < 4; ++ni)
        acc[mi][ni] = __builtin_amdgcn_mfma_f32_16x16x32_bf16(wf[ni], af[mi], acc[mi][ni], 0, 0, 0);
    __builtin_amdgcn_s_setprio(0);
  }

#pragma unroll
  for (int mi = 0; mi < 4; ++mi) {
    const int m = mt * 128 + wm * 64 + mi * 16 + lm;
    float part = 0.f;
#pragma unroll
    for (int ni = 0; ni < 4; ++ni) {
      const int n0 = nt * 128 + wn * 64 + ni * 16 + (rch << 2);
      const f32x4 bb = *reinterpret_cast<const f32x4*>(b1 + n0);
      const f32x4 wv = *reinterpret_cast<const f32x4*>(W2 + n0);
      f32x4 v = acc[mi][ni];
#pragma unroll
      for (int rr = 0; rr < 4; ++rr) part += softplus_fast(v[rr] + bb[rr]) * wv[rr];
    }
    part += __shfl_xor(part, 16);
    part += __shfl_xor(part, 32);
    if (lane < 16) atomicAdd(logits + m, part);
  }
}

// ---------------------------------------------------------------------------
// Per-segment softmax: one block per segment; batch sorted -> binary search.
// (b2 omitted: softmax is shift-invariant.)
// ---------------------------------------------------------------------------
__global__ __launch_bounds__(256) void segsoftmax(const float* __restrict__ logits,
                                                  const int* __restrict__ batch,
                                                  float* __restrict__ out, int N) {
  const int g = blockIdx.x;
  const int tid = threadIdx.x;
  int lo = 0, hi = N;
  while (lo < hi) { int mid = (lo + hi) >> 1; if (batch[mid] < g) lo = mid + 1; else hi = mid; }
  const int beg = lo;
  hi = N;
  while (lo < hi) { int mid = (lo + hi) >> 1; if (batch[mid] < g + 1) lo = mid + 1; else hi = mid; }
  const int end = lo;
  if (beg >= end) return;

  __shared__ float sh[4];
  float m = -INFINITY;
  for (int i = beg + tid; i < end; i += 256) m = fmaxf(m, logits[i]);
#pragma unroll
  for (int o = 32; o; o >>= 1) m = fmaxf(m, __shfl_down(m, o));
  if ((tid & 63) == 0) sh[tid >> 6] = m;
  __syncthreads();
  m = fmaxf(fmaxf(sh[0], sh[1]), fmaxf(sh[2], sh[3]));
  __syncthreads();

  float s = 0.f;
  for (int i = beg + tid; i < end; i += 256) s += expf(logits[i] - m);
#pragma unroll
  for (int o = 32; o; o >>= 1) s += __shfl_down(s, o);
  if ((tid & 63) == 0) sh[tid >> 6] = s;
  __syncthreads();
  s = sh[0] + sh[1] + sh[2] + sh[3];

  const float inv = 1.f / (s + 1e-16f);
  for (int i = beg + tid; i < end; i += 256) out[i] = expf(logits[i] - m) * inv;
}

// ---------------------------------------------------------------------------
extern "C" void kernel_launch(void* const* d_in, const int* in_sizes, int n_in,
                              void* d_out, int out_size, void* d_ws, size_t ws_size,
                              hipStream_t stream) {
  const float* x = (const float*)d_in[0];
  const int* batch = (const int*)d_in[1];
  const float* gx = (const float*)d_in[2];
  const float* W0 = (const float*)d_in[3];
  const float* b0 = (const float*)d_in[4];
  const float* W1 = (const float*)d_in[5];
  const float* b1 = (const float*)d_in[6];
  const float* W2 = (const float*)d_in[7];
  float* out = (float*)d_out;

  const int N = in_sizes[1];                 // 100000
  const int Mp = ((N + 127) / 128) * 128;    // 100096 (mult of 64 and 128)
  const int nwg0 = (Mp / 64) * 2;            // 3128 blocks (gemm0_rf)
  const int nwg1 = (Mp / 128) * 4;           // 3128 blocks (gemm1)

  auto align256 = [](size_t v) { return (v + 255) & ~(size_t)255; };
  char* ws = (char*)d_ws;
  size_t off = 0;
  unsigned short* A0 = (unsigned short*)(ws + off);  off = align256(off + (size_t)Mp * 640 * 2);
  unsigned short* W0T = (unsigned short*)(ws + off); off = align256(off + (size_t)512 * 640 * 2);
  unsigned short* W1T = (unsigned short*)(ws + off); off = align256(off + (size_t)512 * 512 * 2);
  unsigned short* H0 = (unsigned short*)(ws + off);  off = align256(off + (size_t)Mp * 512 * 2);
  float* logits = (float*)(ws + off);                off = align256(off + (size_t)Mp * 4);
  (void)ws_size; (void)n_in; (void)out_size;

  transposeW<620, 640><<<80, 256, 0, stream>>>(W0, W0T);
  transposeW<512, 512><<<64, 256, 0, stream>>>(W1, W1T);
  pack_a0<<<((size_t)Mp * 81 + 255) / 256, 256, 0, stream>>>(x, gx, A0, logits, N, Mp);

  gemm0_rf<<<nwg0, 256, 0, stream>>>(A0, W0T, b0, H0, nwg0);
  gemm1<<<nwg1, 256, 0, stream>>>(H0, W1T, b1, W2, logits, nwg1);

  segsoftmax<<<NSEG, 256, 0, stream>>>(logits, batch, out, N);
}

// Round 13
// 315.562 us; speedup vs baseline: 1.3840x; 1.3840x over previous
//
#include <hip/hip_runtime.h>
#include <hip/hip_bf16.h>
#include <math.h>

// ---------------------------------------------------------------------------
// GATGNN global attention:  softmax_seg( MLP([x|glbl]) )  on MI355X (gfx950)
// R13: R9 kernel bodies + T4 sync skeleton: ring-3 LDS buffers, raw s_barrier,
//      counted vmcnt (6 / 4) -> staging loads span barriers, never drain to 0
//      except tail. gemm0 reads x fp32 directly (no X16 round-trip).
// ---------------------------------------------------------------------------

#define NSEG 1024

typedef __attribute__((ext_vector_type(8))) short short8;
typedef __attribute__((ext_vector_type(4))) float f32x4;

__device__ __forceinline__ unsigned short f2bf(float f) {
  __hip_bfloat16 h = __float2bfloat16(f);
  return *reinterpret_cast<unsigned short*>(&h);
}
__device__ __forceinline__ float softplus_fast(float z) {
  float t = __expf(-fabsf(z));
  return fmaxf(z, 0.f) + __logf(1.f + t);
}
__device__ __forceinline__ void gll16(const void* g, void* l) {
  __builtin_amdgcn_global_load_lds(
      (const __attribute__((address_space(1))) void*)g,
      (__attribute__((address_space(3))) void*)l, 16, 0, 0);
}
// m204 bijective XCD-chunked swizzle: each XCD owns a contiguous L-range.
__device__ __forceinline__ int xcd_swz(int bid, int nwg) {
  int q = nwg >> 3, r = nwg & 7, x = bid & 7, i = bid >> 3;
  return (x < r ? x * (q + 1) : r * (q + 1) + (x - r) * q) + i;
}

// ---------------------------------------------------------------------------
// prep: W0 [620,512] -> W0T bf16 [512,640] (K-pad 0), W1 -> W1T [512,512],
//       zero logits.
// ---------------------------------------------------------------------------
__global__ __launch_bounds__(256) void prep(const float* __restrict__ W0,
                                            const float* __restrict__ W1,
                                            unsigned short* __restrict__ W0T,
                                            unsigned short* __restrict__ W1T,
                                            float* __restrict__ logits, int Mp) {
  int t = blockIdx.x * 256 + threadIdx.x;
  if (t < 512 * 640) {
    int n = t / 640, k = t % 640;
    W0T[t] = f2bf(k < 620 ? W0[(size_t)k * 512 + n] : 0.f);
    return;
  }
  t -= 512 * 640;
  if (t < 512 * 512) {
    int n = t / 512, k = t % 512;
    W1T[t] = f2bf(W1[(size_t)k * 512 + n]);
    return;
  }
  t -= 512 * 512;
  if (t < Mp) logits[t] = 0.f;
}

// ---------------------------------------------------------------------------
// pack_g: gx [N,108] f32 -> G32 [Mp,128] f32 (cols 108..127 and pad rows = 0)
// ---------------------------------------------------------------------------
__global__ __launch_bounds__(256) void pack_g(const float* __restrict__ gx,
                                              float* __restrict__ G32,
                                              int N, int Mp) {
  int t = blockIdx.x * 256 + threadIdx.x;
  if (t >= Mp * 32) return;
  int row = t >> 5, c = (t & 31) << 2;
  float4 v;
  v.x = (row < N && c + 0 < 108) ? gx[(size_t)row * 108 + c + 0] : 0.f;
  v.y = (row < N && c + 1 < 108) ? gx[(size_t)row * 108 + c + 1] : 0.f;
  v.z = (row < N && c + 2 < 108) ? gx[(size_t)row * 108 + c + 2] : 0.f;
  v.w = (row < N && c + 3 < 108) ? gx[(size_t)row * 108 + c + 3] : 0.f;
  *reinterpret_cast<float4*>(G32 + (size_t)row * 128 + c) = v;
}

// ---------------------------------------------------------------------------
// GEMM0: H0 = bf16(softplus([x|G32] * W0T^T + b0)).  128x128 tile, BK=32,
// 4 waves (2x2), 64x64/wave, mfma(w,a) swapped.
//   A: fp32 via global_load_lds, R9 even/odd plane layout (0 conflicts).
//   W: bf16 via global_load_lds, chunk swizzle.
//   Sync: ring-3 buffers; per iter wait vmcnt(6) [stage(kt) landed,
//   stage(kt+1) in flight] -> s_barrier -> issue stage(kt+2). Write-after-
//   read distance 3: buf[(kt+2)%3]'s readers (iter kt-1) retired their
//   ds_reads before the barrier just crossed. Tail: vmcnt(0) at kt=KT-1.
//   LDS 72KB -> 2 blocks/CU; in-wave pipeline does the latency hiding.
// ---------------------------------------------------------------------------
__global__ __launch_bounds__(256, 2) void gemm0(const float* __restrict__ x,
                                                const float* __restrict__ G32,
                                                const unsigned short* __restrict__ W0T,
                                                const float* __restrict__ b0,
                                                unsigned short* __restrict__ H0,
                                                int N, int nwg) {
  constexpr int K = 640, KT = 20;
  __shared__ float Asf[3][128 * 32];            // 16KB x3 (fp32 plane layout)
  __shared__ unsigned short Ws[3][128 * 32];    //  8KB x3 (bf16)
  const int L = xcd_swz(blockIdx.x, nwg);
  const int nt = L & 3, mt = L >> 2;
  const int tid = threadIdx.x, lane = tid & 63, wid = tid >> 6;
  const int wm = wid >> 1, wn = wid & 1, lm = lane & 15, rch = lane >> 4;

  const unsigned short* Wg = W0T + (size_t)(nt * 128) * K;

  f32x4 acc[4][4] = {};

  // A staging: thread f (1024 granules) -> LDS offset f*16B (linear dest).
  // f = rb(3b)|plane(1b)|rr(4b)|cs(2b); fetches granule g=2*(cs^((rr>>1)&3))+pl
  auto stageA = [&](int buf, int kb) {
#pragma unroll
    for (int i2 = 0; i2 < 4; ++i2) {
      int f = i2 * 256 + tid;
      int rb = f >> 7, pl = (f >> 6) & 1, rr = (f >> 2) & 15, cs = f & 3;
      int r = rb * 16 + rr;
      int g = 2 * (cs ^ ((rr >> 1) & 3)) + pl;
      int col = kb + g * 4;
      const float* src;
      if (kb < 512) {
        int rg = mt * 128 + r; if (rg >= N) rg = N - 1;   // clamp; pad rows unread
        src = x + (size_t)rg * 512 + col;
      } else {
        int rg = mt * 128 + r;
        src = G32 + (size_t)rg * 128 + (col - 512);
      }
      gll16(src, &Asf[buf][f * 4]);
    }
  };
  auto stageW = [&](int buf, int kb) {
#pragma unroll
    for (int i2 = 0; i2 < 2; ++i2) {
      int f = i2 * 256 + tid;
      int row = f >> 2;
      int sc = ((f & 3) ^ ((row >> 1) & 3)) << 3;
      gll16(Wg + (size_t)row * K + kb + sc, &Ws[buf][f * 8]);
    }
  };

  // prologue: stage tiles 0,1 (12 ops outstanding)
  stageA(0, 0);  stageW(0, 0);
  stageA(1, 32); stageW(1, 32);

  int cur = 0, stg = 2;
  for (int kt = 0; kt < KT; ++kt) {
    if (kt < KT - 1) asm volatile("s_waitcnt vmcnt(6)" ::: "memory");
    else             asm volatile("s_waitcnt vmcnt(0)" ::: "memory");
    __builtin_amdgcn_s_barrier();

    if (kt + 2 < KT) { stageA(stg, (kt + 2) * 32); stageW(stg, (kt + 2) * 32); }

    const int cs = rch ^ ((lm >> 1) & 3);
    short8 af[4], wf[4];
#pragma unroll
    for (int mi = 0; mi < 4; ++mi) {
      const int rb = wm * 4 + mi;
      const float* base = &Asf[cur][rb * 512 + lm * 16 + cs * 4];
      f32x4 lo = *reinterpret_cast<const f32x4*>(base);        // plane 0
      f32x4 hi = *reinterpret_cast<const f32x4*>(base + 256);  // plane 1
      union { unsigned short u[8]; short8 s8; } cv;
#pragma unroll
      for (int j = 0; j < 4; ++j) { cv.u[j] = f2bf(lo[j]); cv.u[4 + j] = f2bf(hi[j]); }
      af[mi] = cv.s8;
    }
#pragma unroll
    for (int ni = 0; ni < 4; ++ni) {
      int rw = wn * 64 + ni * 16 + lm;
      wf[ni] = *reinterpret_cast<const short8*>(
          &Ws[cur][rw * 32 + ((rch ^ ((rw >> 1) & 3)) << 3)]);
    }
    __builtin_amdgcn_s_setprio(1);
#pragma unroll
    for (int mi = 0; mi < 4; ++mi)
#pragma unroll
      for (int ni = 0; ni < 4; ++ni)
        acc[mi][ni] = __builtin_amdgcn_mfma_f32_16x16x32_bf16(wf[ni], af[mi], acc[mi][ni], 0, 0, 0);
    __builtin_amdgcn_s_setprio(0);

    cur = (cur == 2) ? 0 : cur + 1;
    stg = (stg == 2) ? 0 : stg + 1;
  }

  // epilogue: thread holds C[m][n0..n0+3]
#pragma unroll
  for (int mi = 0; mi < 4; ++mi) {
    const int m = mt * 128 + wm * 64 + mi * 16 + lm;
#pragma unroll
    for (int ni = 0; ni < 4; ++ni) {
      const int n0 = nt * 128 + wn * 64 + ni * 16 + (rch << 2);
      const f32x4 bb = *reinterpret_cast<const f32x4*>(b0 + n0);
      f32x4 v = acc[mi][ni];
      union { unsigned short u[4]; uint2 qv; } o;
#pragma unroll
      for (int rr = 0; rr < 4; ++rr) o.u[rr] = f2bf(softplus_fast(v[rr] + bb[rr]));
      *reinterpret_cast<uint2*>(H0 + (size_t)m * 512 + n0) = o.qv;
    }
  }
}

// ---------------------------------------------------------------------------
// GEMM1 (+logit fusion): logits[m] += sum_n softplus(H0*W1T^T + b1)[m][n]*W2[n]
// Same ring-3 counted-vmcnt skeleton; both panels bf16 (4 ops/iter -> vmcnt 4).
// 48KB LDS -> 3 blocks/CU.
// ---------------------------------------------------------------------------
__global__ __launch_bounds__(256, 3) void gemm1(const unsigned short* __restrict__ H0,
                                                const unsigned short* __restrict__ W1T,
                                                const float* __restrict__ b1,
                                                const float* __restrict__ W2,
                                                float* __restrict__ logits, int nwg) {
  constexpr int K = 512, KT = 16;
  __shared__ unsigned short As[3][128 * 32];
  __shared__ unsigned short Ws[3][128 * 32];
  const int L = xcd_swz(blockIdx.x, nwg);
  const int nt = L & 3, mt = L >> 2;
  const int tid = threadIdx.x, lane = tid & 63, wid = tid >> 6;
  const int wm = wid >> 1, wn = wid & 1, lm = lane & 15, rch = lane >> 4;

  const unsigned short* Ag = H0 + (size_t)(mt * 128) * K;
  const unsigned short* Wg = W1T + (size_t)(nt * 128) * K;

  f32x4 acc[4][4] = {};

  auto stage = [&](int buf, int kb) {
#pragma unroll
    for (int i2 = 0; i2 < 2; ++i2) {
      int f = i2 * 256 + tid;
      int row = f >> 2;
      int sc = ((f & 3) ^ ((row >> 1) & 3)) << 3;
      gll16(Ag + (size_t)row * K + kb + sc, &As[buf][f * 8]);
      gll16(Wg + (size_t)row * K + kb + sc, &Ws[buf][f * 8]);
    }
  };

  stage(0, 0);
  stage(1, 32);

  int cur = 0, stg = 2;
  for (int kt = 0; kt < KT; ++kt) {
    if (kt < KT - 1) asm volatile("s_waitcnt vmcnt(4)" ::: "memory");
    else             asm volatile("s_waitcnt vmcnt(0)" ::: "memory");
    __builtin_amdgcn_s_barrier();

    if (kt + 2 < KT) stage(stg, (kt + 2) * 32);

    short8 af[4], wf[4];
#pragma unroll
    for (int mi = 0; mi < 4; ++mi) {
      int rw = wm * 64 + mi * 16 + lm;
      af[mi] = *reinterpret_cast<const short8*>(
          &As[cur][rw * 32 + ((rch ^ ((rw >> 1) & 3)) << 3)]);
    }
#pragma unroll
    for (int ni = 0; ni < 4; ++ni) {
      int rw = wn * 64 + ni * 16 + lm;
      wf[ni] = *reinterpret_cast<const short8*>(
          &Ws[cur][rw * 32 + ((rch ^ ((rw >> 1) & 3)) << 3)]);
    }
    __builtin_amdgcn_s_setprio(1);
#pragma unroll
    for (int mi = 0; mi < 4; ++mi)
#pragma unroll
      for (int ni = 0; ni < 4; ++ni)
        acc[mi][ni] = __builtin_amdgcn_mfma_f32_16x16x32_bf16(wf[ni], af[mi], acc[mi][ni], 0, 0, 0);
    __builtin_amdgcn_s_setprio(0);

    cur = (cur == 2) ? 0 : cur + 1;
    stg = (stg == 2) ? 0 : stg + 1;
  }

#pragma unroll
  for (int mi = 0; mi < 4; ++mi) {
    const int m = mt * 128 + wm * 64 + mi * 16 + lm;
    float part = 0.f;
#pragma unroll
    for (int ni = 0; ni < 4; ++ni) {
      const int n0 = nt * 128 + wn * 64 + ni * 16 + (rch << 2);
      const f32x4 bb = *reinterpret_cast<const f32x4*>(b1 + n0);
      const f32x4 wv = *reinterpret_cast<const f32x4*>(W2 + n0);
      f32x4 v = acc[mi][ni];
#pragma unroll
      for (int rr = 0; rr < 4; ++rr) part += softplus_fast(v[rr] + bb[rr]) * wv[rr];
    }
    part += __shfl_xor(part, 16);
    part += __shfl_xor(part, 32);
    if (lane < 16) atomicAdd(logits + m, part);
  }
}

// ---------------------------------------------------------------------------
// Per-segment softmax: one block per segment; batch sorted -> binary search.
// (b2 omitted: softmax is shift-invariant.)
// ---------------------------------------------------------------------------
__global__ __launch_bounds__(256) void segsoftmax(const float* __restrict__ logits,
                                                  const int* __restrict__ batch,
                                                  float* __restrict__ out, int N) {
  const int g = blockIdx.x;
  const int tid = threadIdx.x;
  int lo = 0, hi = N;
  while (lo < hi) { int mid = (lo + hi) >> 1; if (batch[mid] < g) lo = mid + 1; else hi = mid; }
  const int beg = lo;
  hi = N;
  while (lo < hi) { int mid = (lo + hi) >> 1; if (batch[mid] < g + 1) lo = mid + 1; else hi = mid; }
  const int end = lo;
  if (beg >= end) return;

  __shared__ float sh[4];
  float m = -INFINITY;
  for (int i = beg + tid; i < end; i += 256) m = fmaxf(m, logits[i]);
#pragma unroll
  for (int o = 32; o; o >>= 1) m = fmaxf(m, __shfl_down(m, o));
  if ((tid & 63) == 0) sh[tid >> 6] = m;
  __syncthreads();
  m = fmaxf(fmaxf(sh[0], sh[1]), fmaxf(sh[2], sh[3]));
  __syncthreads();

  float s = 0.f;
  for (int i = beg + tid; i < end; i += 256) s += expf(logits[i] - m);
#pragma unroll
  for (int o = 32; o; o >>= 1) s += __shfl_down(s, o);
  if ((tid & 63) == 0) sh[tid >> 6] = s;
  __syncthreads();
  s = sh[0] + sh[1] + sh[2] + sh[3];

  const float inv = 1.f / (s + 1e-16f);
  for (int i = beg + tid; i < end; i += 256) out[i] = expf(logits[i] - m) * inv;
}

// ---------------------------------------------------------------------------
extern "C" void kernel_launch(void* const* d_in, const int* in_sizes, int n_in,
                              void* d_out, int out_size, void* d_ws, size_t ws_size,
                              hipStream_t stream) {
  const float* x = (const float*)d_in[0];
  const int* batch = (const int*)d_in[1];
  const float* gx = (const float*)d_in[2];
  const float* W0 = (const float*)d_in[3];
  const float* b0 = (const float*)d_in[4];
  const float* W1 = (const float*)d_in[5];
  const float* b1 = (const float*)d_in[6];
  const float* W2 = (const float*)d_in[7];
  float* out = (float*)d_out;

  const int N = in_sizes[1];                 // 100000
  const int Mp = ((N + 127) / 128) * 128;    // 100096
  const int nwg = (Mp / 128) * 4;            // 3128 blocks per GEMM (3128%8==0)

  auto align256 = [](size_t v) { return (v + 255) & ~(size_t)255; };
  char* ws = (char*)d_ws;
  size_t off = 0;
  float* G32 = (float*)(ws + off);                   off = align256(off + (size_t)Mp * 128 * 4);
  unsigned short* W0T = (unsigned short*)(ws + off); off = align256(off + (size_t)512 * 640 * 2);
  unsigned short* W1T = (unsigned short*)(ws + off); off = align256(off + (size_t)512 * 512 * 2);
  unsigned short* H0 = (unsigned short*)(ws + off);  off = align256(off + (size_t)Mp * 512 * 2);
  float* logits = (float*)(ws + off);                off = align256(off + (size_t)Mp * 4);
  (void)ws_size; (void)n_in; (void)out_size;

  const int prep_elems = 512 * 640 + 512 * 512 + Mp;
  prep<<<(prep_elems + 255) / 256, 256, 0, stream>>>(W0, W1, W0T, W1T, logits, Mp);
  pack_g<<<(Mp * 32 + 255) / 256, 256, 0, stream>>>(gx, G32, N, Mp);

  gemm0<<<nwg, 256, 0, stream>>>(x, G32, W0T, b0, H0, N, nwg);
  gemm1<<<nwg, 256, 0, stream>>>(H0, W1T, b1, W2, logits, nwg);

  segsoftmax<<<NSEG, 256, 0, stream>>>(logits, batch, out, N);
}

// Round 14
// 304.141 us; speedup vs baseline: 1.4360x; 1.0376x over previous
//
#include <hip/hip_runtime.h>
#include <hip/hip_bf16.h>
#include <math.h>

// ---------------------------------------------------------------------------
// GATGNN global attention:  softmax_seg( MLP([x|glbl]) )  on MI355X (gfx950)
// R14: producer-consumer CHUNKING for L3 locality: [pack_i -> gemm0_i ->
//      gemm1_i] x2 over M halves (~215MB working set per chunk < 256MB L3).
//      Kernel bodies = proven R6 (128x128, BK=32, gll16 both panels,
//      conflict-free chunk swizzle, 4 blk/CU, XCD swizzle, setprio).
// ---------------------------------------------------------------------------

#define NSEG 1024

typedef __attribute__((ext_vector_type(8))) short short8;
typedef __attribute__((ext_vector_type(4))) float f32x4;

__device__ __forceinline__ unsigned short f2bf(float f) {
  __hip_bfloat16 h = __float2bfloat16(f);
  return *reinterpret_cast<unsigned short*>(&h);
}
__device__ __forceinline__ float softplus_fast(float z) {
  float t = __expf(-fabsf(z));
  return fmaxf(z, 0.f) + __logf(1.f + t);
}
__device__ __forceinline__ void gll16(const void* g, void* l) {
  __builtin_amdgcn_global_load_lds(
      (const __attribute__((address_space(1))) void*)g,
      (__attribute__((address_space(3))) void*)l, 16, 0, 0);
}
// m204 bijective XCD-chunked swizzle (any nwg): each XCD owns a contiguous
// range of L.
__device__ __forceinline__ int xcd_swz(int bid, int nwg) {
  int q = nwg >> 3, r = nwg & 7, x = bid & 7, i = bid >> 3;
  return (x < r ? x * (q + 1) : r * (q + 1) + (x - r) * q) + i;
}

// ---------------------------------------------------------------------------
// prep: W0 [620,512] -> W0T bf16 [512,640] (K-pad 0), W1 -> W1T [512,512],
//       zero logits.
// ---------------------------------------------------------------------------
__global__ __launch_bounds__(256) void prep(const float* __restrict__ W0,
                                            const float* __restrict__ W1,
                                            unsigned short* __restrict__ W0T,
                                            unsigned short* __restrict__ W1T,
                                            float* __restrict__ logits, int Mp) {
  int t = blockIdx.x * 256 + threadIdx.x;
  if (t < 512 * 640) {
    int n = t / 640, k = t % 640;
    W0T[t] = f2bf(k < 620 ? W0[(size_t)k * 512 + n] : 0.f);
    return;
  }
  t -= 512 * 640;
  if (t < 512 * 512) {
    int n = t / 512, k = t % 512;
    W1T[t] = f2bf(W1[(size_t)k * 512 + n]);
    return;
  }
  t -= 512 * 512;
  if (t < Mp) logits[t] = 0.f;
}

// ---------------------------------------------------------------------------
// pack (row-range): x -> X16 [Mp,512] bf16 ; gx -> G16 [Mp,128] bf16
// for rows [r0, r0+rows). Pad rows (>=N) zeroed. 16B stores.
// ---------------------------------------------------------------------------
__global__ __launch_bounds__(256) void pack(const float* __restrict__ x,
                                            const float* __restrict__ gx,
                                            unsigned short* __restrict__ X16,
                                            unsigned short* __restrict__ G16,
                                            int N, int r0, int rows) {
  int t = blockIdx.x * 256 + threadIdx.x;
  union { unsigned short u[8]; uint4 q; } v;
  if (t < rows * 64) {
    int row = r0 + (t >> 6), c = t & 63;
    if (row >= N) {
#pragma unroll
      for (int j = 0; j < 8; ++j) v.u[j] = 0;
    } else {
      const float4* p = (const float4*)(x + (size_t)row * 512 + c * 8);
      float4 a = p[0], b = p[1];
      v.u[0] = f2bf(a.x); v.u[1] = f2bf(a.y); v.u[2] = f2bf(a.z); v.u[3] = f2bf(a.w);
      v.u[4] = f2bf(b.x); v.u[5] = f2bf(b.y); v.u[6] = f2bf(b.z); v.u[7] = f2bf(b.w);
    }
    *reinterpret_cast<uint4*>(X16 + (size_t)row * 512 + c * 8) = v.q;
    return;
  }
  t -= rows * 64;
  if (t < rows * 16) {
    int row = r0 + (t >> 4), c = t & 15;
#pragma unroll
    for (int j = 0; j < 8; ++j) {
      int col = c * 8 + j;
      v.u[j] = (row < N && col < 108) ? f2bf(gx[(size_t)row * 108 + col]) : 0;
    }
    *reinterpret_cast<uint4*>(G16 + (size_t)row * 128 + c * 8) = v.q;
  }
}

// ---------------------------------------------------------------------------
// GEMM: Z[M,512] = A[M,K] * WT[512,K]^T + bias; 128x128 tile, BK=32, 4 waves
// (2x2), 64x64/wave, mfma(w,a) swapped -> thread holds 4 consecutive output
// columns. Both panels via global_load_lds, pre-swizzled source (chunk c of
// local row r -> slot c^((r>>1)&3), conflict-free ds_read_b128). 32KB LDS,
// 4 blocks/CU.  Row-range via mt_base (chunked launches).
//  SPLITA: A = [A1 (stride 512) | A2 (stride 128)], boundary at k=512.
//  FUSE=false: C = bf16(softplus(Z))                       (layer 0 -> H0)
//  FUSE=true : logits[m] += sum_n softplus(Z[m,n])*W2[n]   (layers 1+2)
// ---------------------------------------------------------------------------
template <int K, bool SPLITA, bool FUSE>
__global__ __launch_bounds__(256, 4) void gemm_bf16(const unsigned short* __restrict__ A1,
                                                    const unsigned short* __restrict__ A2,
                                                    const unsigned short* __restrict__ WT,
                                                    const float* __restrict__ bias,
                                                    unsigned short* __restrict__ C,
                                                    const float* __restrict__ W2,
                                                    float* __restrict__ logits,
                                                    int nwg, int mt_base) {
  constexpr int KT = K / 32;
  __shared__ unsigned short As[2][128 * 32];
  __shared__ unsigned short Ws[2][128 * 32];
  const int L = xcd_swz(blockIdx.x, nwg);
  const int nt = L & 3, mt = mt_base + (L >> 2);
  const int tid = threadIdx.x, lane = tid & 63, wid = tid >> 6;
  const int wm = wid >> 1, wn = wid & 1, lm = lane & 15, rch = lane >> 4;

  const unsigned short* Ag = A1 + (size_t)(mt * 128) * 512;
  const unsigned short* A2g = SPLITA ? A2 + (size_t)(mt * 128) * 128 : nullptr;
  const unsigned short* Wg = WT + (size_t)(nt * 128) * K;

  f32x4 acc[4][4] = {};

  auto stage = [&](int buf, int kb) {
#pragma unroll
    for (int i2 = 0; i2 < 2; ++i2) {
      int f = i2 * 256 + tid;
      int row = f >> 2;
      int sc = ((f & 3) ^ ((row >> 1) & 3)) << 3;  // pre-swizzled source, linear dest
      if constexpr (SPLITA) {
        if (kb < 512) gll16(Ag + (size_t)row * 512 + kb + sc, &As[buf][f * 8]);
        else          gll16(A2g + (size_t)row * 128 + (kb - 512) + sc, &As[buf][f * 8]);
      } else {
        gll16(Ag + (size_t)row * 512 + kb + sc, &As[buf][f * 8]);
      }
      gll16(Wg + (size_t)row * K + kb + sc, &Ws[buf][f * 8]);
    }
  };

  stage(0, 0);

  for (int kt = 0; kt < KT; ++kt) {
    const int cur = kt & 1;
    __syncthreads();  // buf[cur] staged; buf[cur^1] readers done
    if (kt + 1 < KT) stage(cur ^ 1, (kt + 1) * 32);

    short8 af[4], wf[4];
#pragma unroll
    for (int mi = 0; mi < 4; ++mi) {
      int rw = wm * 64 + mi * 16 + lm;
      af[mi] = *reinterpret_cast<const short8*>(
          &As[cur][rw * 32 + ((rch ^ ((rw >> 1) & 3)) << 3)]);
    }
#pragma unroll
    for (int ni = 0; ni < 4; ++ni) {
      int rw = wn * 64 + ni * 16 + lm;
      wf[ni] = *reinterpret_cast<const short8*>(
          &Ws[cur][rw * 32 + ((rch ^ ((rw >> 1) & 3)) << 3)]);
    }
    __builtin_amdgcn_s_setprio(1);
#pragma unroll
    for (int mi = 0; mi < 4; ++mi)
#pragma unroll
      for (int ni = 0; ni < 4; ++ni)
        acc[mi][ni] = __builtin_amdgcn_mfma_f32_16x16x32_bf16(wf[ni], af[mi], acc[mi][ni], 0, 0, 0);
    __builtin_amdgcn_s_setprio(0);
  }

  // Transposed D layout: thread holds C[m][n0..n0+3]
#pragma unroll
  for (int mi = 0; mi < 4; ++mi) {
    const int m = mt * 128 + wm * 64 + mi * 16 + lm;
    float part = 0.f;
#pragma unroll
    for (int ni = 0; ni < 4; ++ni) {
      const int n0 = nt * 128 + wn * 64 + ni * 16 + (rch << 2);
      const f32x4 bb = *reinterpret_cast<const f32x4*>(bias + n0);
      f32x4 v = acc[mi][ni];
      if constexpr (!FUSE) {
        union { unsigned short u[4]; uint2 qv; } o;
#pragma unroll
        for (int rr = 0; rr < 4; ++rr) o.u[rr] = f2bf(softplus_fast(v[rr] + bb[rr]));
        *reinterpret_cast<uint2*>(C + (size_t)m * 512 + n0) = o.qv;
      } else {
        const f32x4 wv = *reinterpret_cast<const f32x4*>(W2 + n0);
#pragma unroll
        for (int rr = 0; rr < 4; ++rr) part += softplus_fast(v[rr] + bb[rr]) * wv[rr];
      }
    }
    if constexpr (FUSE) {
      part += __shfl_xor(part, 16);
      part += __shfl_xor(part, 32);
      if (lane < 16) atomicAdd(logits + m, part);
    }
  }
}

// ---------------------------------------------------------------------------
// Per-segment softmax: one block per segment; batch sorted -> binary search.
// (b2 omitted: softmax is shift-invariant.)
// ---------------------------------------------------------------------------
__global__ __launch_bounds__(256) void segsoftmax(const float* __restrict__ logits,
                                                  const int* __restrict__ batch,
                                                  float* __restrict__ out, int N) {
  const int g = blockIdx.x;
  const int tid = threadIdx.x;
  int lo = 0, hi = N;
  while (lo < hi) { int mid = (lo + hi) >> 1; if (batch[mid] < g) lo = mid + 1; else hi = mid; }
  const int beg = lo;
  hi = N;
  while (lo < hi) { int mid = (lo + hi) >> 1; if (batch[mid] < g + 1) lo = mid + 1; else hi = mid; }
  const int end = lo;
  if (beg >= end) return;

  __shared__ float sh[4];
  float m = -INFINITY;
  for (int i = beg + tid; i < end; i += 256) m = fmaxf(m, logits[i]);
#pragma unroll
  for (int o = 32; o; o >>= 1) m = fmaxf(m, __shfl_down(m, o));
  if ((tid & 63) == 0) sh[tid >> 6] = m;
  __syncthreads();
  m = fmaxf(fmaxf(sh[0], sh[1]), fmaxf(sh[2], sh[3]));
  __syncthreads();

  float s = 0.f;
  for (int i = beg + tid; i < end; i += 256) s += expf(logits[i] - m);
#pragma unroll
  for (int o = 32; o; o >>= 1) s += __shfl_down(s, o);
  if ((tid & 63) == 0) sh[tid >> 6] = s;
  __syncthreads();
  s = sh[0] + sh[1] + sh[2] + sh[3];

  const float inv = 1.f / (s + 1e-16f);
  for (int i = beg + tid; i < end; i += 256) out[i] = expf(logits[i] - m) * inv;
}

// ---------------------------------------------------------------------------
extern "C" void kernel_launch(void* const* d_in, const int* in_sizes, int n_in,
                              void* d_out, int out_size, void* d_ws, size_t ws_size,
                              hipStream_t stream) {
  const float* x = (const float*)d_in[0];
  const int* batch = (const int*)d_in[1];
  const float* gx = (const float*)d_in[2];
  const float* W0 = (const float*)d_in[3];
  const float* b0 = (const float*)d_in[4];
  const float* W1 = (const float*)d_in[5];
  const float* b1 = (const float*)d_in[6];
  const float* W2 = (const float*)d_in[7];
  float* out = (float*)d_out;

  const int N = in_sizes[1];                 // 100000
  const int Mp = ((N + 127) / 128) * 128;    // 100096
  const int blocksM = Mp / 128;              // 782

  auto align256 = [](size_t v) { return (v + 255) & ~(size_t)255; };
  char* ws = (char*)d_ws;
  size_t off = 0;
  unsigned short* X16 = (unsigned short*)(ws + off); off = align256(off + (size_t)Mp * 512 * 2);
  unsigned short* G16 = (unsigned short*)(ws + off); off = align256(off + (size_t)Mp * 128 * 2);
  unsigned short* W0T = (unsigned short*)(ws + off); off = align256(off + (size_t)512 * 640 * 2);
  unsigned short* W1T = (unsigned short*)(ws + off); off = align256(off + (size_t)512 * 512 * 2);
  unsigned short* H0 = (unsigned short*)(ws + off);  off = align256(off + (size_t)Mp * 512 * 2);
  float* logits = (float*)(ws + off);                off = align256(off + (size_t)Mp * 4);
  (void)ws_size; (void)n_in; (void)out_size;

  const int prep_elems = 512 * 640 + 512 * 512 + Mp;
  prep<<<(prep_elems + 255) / 256, 256, 0, stream>>>(W0, W1, W0T, W1T, logits, Mp);

  // chunked producer-consumer: per-chunk working set fits L3 (256MB)
  const int NCHUNK = 2;
  const int mb0 = blocksM / NCHUNK;           // 391
  for (int c = 0; c < NCHUNK; ++c) {
    const int mtb = c * mb0;
    const int mbc = (c == NCHUNK - 1) ? (blocksM - mtb) : mb0;
    const int r0 = mtb * 128, rows = mbc * 128;
    const int nwgc = mbc * 4;

    pack<<<(rows * 80 + 255) / 256, 256, 0, stream>>>(x, gx, X16, G16, N, r0, rows);
    gemm_bf16<640, true, false><<<nwgc, 256, 0, stream>>>(
        X16, G16, W0T, b0, H0, nullptr, nullptr, nwgc, mtb);
    gemm_bf16<512, false, true><<<nwgc, 256, 0, stream>>>(
        H0, nullptr, W1T, b1, nullptr, W2, logits, nwgc, mtb);
  }

  segsoftmax<<<NSEG, 256, 0, stream>>>(logits, batch, out, N);
}